// Round 6
// baseline (160.663 us; speedup 1.0000x reference)
//
#include <hip/hip_runtime.h>
#include <stdint.h>
#include <stddef.h>

typedef int v4i __attribute__((ext_vector_type(4)));

#define GLOAD_LDS16(g, l) __builtin_amdgcn_global_load_lds( \
    (const __attribute__((address_space(1))) void*)(g),     \
    (__attribute__((address_space(3))) void*)(l), 16, 0, 0)

// ---------------------------------------------------------------------------
// Quantize rows of length 2048: one wave per row, 4 rows per 256-thread block.
// scale = max(amax/127, floorv); q = clip(rint(v/scale), -128, 127)
// ---------------------------------------------------------------------------
__device__ __forceinline__ int pack4(float4 f, float s) {
    int a = (int)rintf(f.x / s); a = a < -128 ? -128 : (a > 127 ? 127 : a);
    int b = (int)rintf(f.y / s); b = b < -128 ? -128 : (b > 127 ? 127 : b);
    int c = (int)rintf(f.z / s); c = c < -128 ? -128 : (c > 127 ? 127 : c);
    int d = (int)rintf(f.w / s); d = d < -128 ? -128 : (d > 127 ? 127 : d);
    return (a & 255) | ((b & 255) << 8) | ((c & 255) << 16) | ((d & 255) << 24);
}

__global__ __launch_bounds__(256) void quant_rows_2048(
    const float* __restrict__ in, signed char* __restrict__ q,
    float* __restrict__ scales, float floorv)
{
    const int lane = threadIdx.x & 63;
    const int row  = blockIdx.x * 4 + (threadIdx.x >> 6);
    const float* rp = in + (size_t)row * 2048;

    float4 v[8];
#pragma unroll
    for (int j = 0; j < 2; ++j) {
        const float4* p = (const float4*)(rp + j * 1024 + lane * 16);
#pragma unroll
        for (int i = 0; i < 4; ++i) v[j * 4 + i] = p[i];
    }
    float am = 0.0f;
#pragma unroll
    for (int i = 0; i < 8; ++i) {
        am = fmaxf(am, fabsf(v[i].x));
        am = fmaxf(am, fabsf(v[i].y));
        am = fmaxf(am, fabsf(v[i].z));
        am = fmaxf(am, fabsf(v[i].w));
    }
#pragma unroll
    for (int off = 32; off; off >>= 1) am = fmaxf(am, __shfl_xor(am, off));
    const float s = fmaxf(am / 127.0f, floorv);

#pragma unroll
    for (int j = 0; j < 2; ++j) {
        int4 pk;
        pk.x = pack4(v[j * 4 + 0], s);
        pk.y = pack4(v[j * 4 + 1], s);
        pk.z = pack4(v[j * 4 + 2], s);
        pk.w = pack4(v[j * 4 + 3], s);
        *(int4*)(q + (size_t)row * 2048 + j * 1024 + lane * 16) = pk;
    }
    if (lane == 0) scales[row] = s;
}

// ---------------------------------------------------------------------------
// int8 GEMM — barrier-paired phases with READS ONE PHASE AHEAD + counted
// lgkmcnt (the actual m201/T4 combination):
//   P0(t): issue 4 reads (A t,m4..7) | stage A(t+3) | BAR | lgkm(4) | 16 MFMA
//          on regs from last phase | BAR
//   P1(t): issue 8 reads (B(t+1), A(t+1) m0..3) | stage B(t+3) | BAR |
//          lgkm(8) (drains exactly P0's 4 A-reads) | 16 MFMA | vmcnt(4)
//          counted (t+1 AND t+2 resident; tail 4->0) | BAR
// The next phase's LDS drain overlaps this phase's MFMA cluster.
// 256x256 tile, BK=64, 8 waves (2Mx4N), per-wave 128x64, mfma_i32_16x16x64_i8,
// ring-4 LDS (128 KB). Swizzle: slot s of row r holds chunk s ^ ((r>>1)&3).
// ---------------------------------------------------------------------------
__global__ __launch_bounds__(512, 2) void gemm_i8_pipe(
    const signed char* __restrict__ xq, const signed char* __restrict__ wq,
    const float* __restrict__ xs, const float* __restrict__ ws,
    const float* __restrict__ bias, float* __restrict__ out, int K)
{
    __shared__ __align__(16) signed char lds[131072]; // [A:4x16KB][B:4x16KB]

    const int tid  = threadIdx.x;
    const int lane = tid & 63;
    const int wid  = tid >> 6;
    const int wm   = wid >> 2;        // 0..1
    const int wn   = wid & 3;         // 0..3

    const int nwg  = gridDim.x * gridDim.y;
    int orig = blockIdx.y * gridDim.x + blockIdx.x;
    int swz  = ((nwg & 7) == 0) ? ((orig & 7) * (nwg >> 3) + (orig >> 3)) : orig;
    const int brow = (swz / gridDim.x) * 256;
    const int bcol = (swz % gridDim.x) * 256;

    const int srow = tid >> 2;                                   // 0..127
    const int gch  = (((tid & 3) ^ ((tid >> 3) & 3)) << 4);      // swizzled src byte
    const int lofs = tid << 4;                                   // linear LDS dest
    const signed char* gA = xq + (size_t)(brow + srow) * K;
    const signed char* gB = wq + (size_t)(bcol + srow) * K;

#define ST_A(tt, half) GLOAD_LDS16(gA + (size_t)(half) * 128 * K + (size_t)(tt) * 64 + gch, \
                                   lds + ((((tt) & 3) << 14) + ((half) << 13) + lofs))
#define ST_B(tt, half) GLOAD_LDS16(gB + (size_t)(half) * 128 * K + (size_t)(tt) * 64 + gch, \
                                   lds + (65536 + (((tt) & 3) << 14) + ((half) << 13) + lofs))

    const int rl   = lane & 15;
    const int ko   = lane >> 4;
    const int slot = ((ko ^ ((rl >> 1) & 3)) << 4);

#define FRAG_A(buf, r) (*(const volatile v4i*)(lds + (((buf) << 14) + (r) * 64 + slot)))
#define FRAG_B(buf, r) (*(const volatile v4i*)(lds + (65536 + ((buf) << 14) + (r) * 64 + slot)))

    v4i acc[8][4] = {};
    const int ar = wm * 128 + rl;
    const int br = wn * 64 + rl;

#define MFMA16(MB, A0, A1, A2, A3)                                                      \
    do {                                                                                \
        __builtin_amdgcn_s_setprio(1);                                                  \
        acc[MB+0][0] = __builtin_amdgcn_mfma_i32_16x16x64_i8(A0, bc0, acc[MB+0][0], 0, 0, 0); \
        acc[MB+0][1] = __builtin_amdgcn_mfma_i32_16x16x64_i8(A0, bc1, acc[MB+0][1], 0, 0, 0); \
        acc[MB+0][2] = __builtin_amdgcn_mfma_i32_16x16x64_i8(A0, bc2, acc[MB+0][2], 0, 0, 0); \
        acc[MB+0][3] = __builtin_amdgcn_mfma_i32_16x16x64_i8(A0, bc3, acc[MB+0][3], 0, 0, 0); \
        acc[MB+1][0] = __builtin_amdgcn_mfma_i32_16x16x64_i8(A1, bc0, acc[MB+1][0], 0, 0, 0); \
        acc[MB+1][1] = __builtin_amdgcn_mfma_i32_16x16x64_i8(A1, bc1, acc[MB+1][1], 0, 0, 0); \
        acc[MB+1][2] = __builtin_amdgcn_mfma_i32_16x16x64_i8(A1, bc2, acc[MB+1][2], 0, 0, 0); \
        acc[MB+1][3] = __builtin_amdgcn_mfma_i32_16x16x64_i8(A1, bc3, acc[MB+1][3], 0, 0, 0); \
        acc[MB+2][0] = __builtin_amdgcn_mfma_i32_16x16x64_i8(A2, bc0, acc[MB+2][0], 0, 0, 0); \
        acc[MB+2][1] = __builtin_amdgcn_mfma_i32_16x16x64_i8(A2, bc1, acc[MB+2][1], 0, 0, 0); \
        acc[MB+2][2] = __builtin_amdgcn_mfma_i32_16x16x64_i8(A2, bc2, acc[MB+2][2], 0, 0, 0); \
        acc[MB+2][3] = __builtin_amdgcn_mfma_i32_16x16x64_i8(A2, bc3, acc[MB+2][3], 0, 0, 0); \
        acc[MB+3][0] = __builtin_amdgcn_mfma_i32_16x16x64_i8(A3, bc0, acc[MB+3][0], 0, 0, 0); \
        acc[MB+3][1] = __builtin_amdgcn_mfma_i32_16x16x64_i8(A3, bc1, acc[MB+3][1], 0, 0, 0); \
        acc[MB+3][2] = __builtin_amdgcn_mfma_i32_16x16x64_i8(A3, bc2, acc[MB+3][2], 0, 0, 0); \
        acc[MB+3][3] = __builtin_amdgcn_mfma_i32_16x16x64_i8(A3, bc3, acc[MB+3][3], 0, 0, 0); \
        __builtin_amdgcn_s_setprio(0);                                                  \
    } while (0)

#define BAR()    __builtin_amdgcn_s_barrier()
#define LGKM(N)  do { asm volatile("s_waitcnt lgkmcnt(" #N ")" ::: "memory"); \
                      __builtin_amdgcn_sched_barrier(0); } while (0)

    // ---- prologue: stage tiles 0,1,2; vmcnt(4) => tiles 0,1 resident
    ST_A(0, 0); ST_A(0, 1); ST_B(0, 0); ST_B(0, 1);
    ST_A(1, 0); ST_A(1, 1); ST_B(1, 0); ST_B(1, 1);
    ST_A(2, 0); ST_A(2, 1); ST_B(2, 0); ST_B(2, 1);
    asm volatile("s_waitcnt vmcnt(4)" ::: "memory");
    BAR();

    // prologue reads for P0(0): B(0) + A(0) m0..3  (8 reads, left in flight)
    v4i bc0 = FRAG_B(0, br);
    v4i bc1 = FRAG_B(0, br + 16);
    v4i bc2 = FRAG_B(0, br + 32);
    v4i bc3 = FRAG_B(0, br + 48);
    v4i af0 = FRAG_A(0, ar);
    v4i af1 = FRAG_A(0, ar + 16);
    v4i af2 = FRAG_A(0, ar + 32);
    v4i af3 = FRAG_A(0, ar + 48);
    v4i an0, an1, an2, an3, bn0, bn1, bn2, bn3;

    const int NT = K >> 6;   // 32
    for (int t = 0; t < NT; ++t) {
        const int buf  = t & 3;
        const int nbuf = (t + 1) & 3;
        const bool st  = (t + 3 < NT);
        // ---- P0: issue A(t, m4..7); stage A(t+3); MFMA on af (loaded last phase)
        an0 = FRAG_A(buf, ar + 64);
        an1 = FRAG_A(buf, ar + 80);
        an2 = FRAG_A(buf, ar + 96);
        an3 = FRAG_A(buf, ar + 112);
        if (st) { ST_A(t + 3, 0); ST_A(t + 3, 1); }
        BAR(); LGKM(4);
        MFMA16(0, af0, af1, af2, af3);
        BAR();
        // ---- P1: issue B(t+1) + A(t+1, m0..3); stage B(t+3); MFMA on an
        bn0 = FRAG_B(nbuf, br);
        bn1 = FRAG_B(nbuf, br + 16);
        bn2 = FRAG_B(nbuf, br + 32);
        bn3 = FRAG_B(nbuf, br + 48);
        af0 = FRAG_A(nbuf, ar);
        af1 = FRAG_A(nbuf, ar + 16);
        af2 = FRAG_A(nbuf, ar + 32);
        af3 = FRAG_A(nbuf, ar + 48);
        if (st) { ST_B(t + 3, 0); ST_B(t + 3, 1); }
        BAR(); LGKM(8);
        MFMA16(4, an0, an1, an2, an3);
        if (t <= NT - 4)      asm volatile("s_waitcnt vmcnt(4)" ::: "memory");
        else if (t == NT - 3) asm volatile("s_waitcnt vmcnt(0)" ::: "memory");
        BAR();
        bc0 = bn0; bc1 = bn1; bc2 = bn2; bc3 = bn3;
    }

    // ---- epilogue: C/D layout col = lane&15, row = (lane>>4)*4 + j
    const int rg = lane >> 4;
#pragma unroll
    for (int n = 0; n < 4; ++n) {
        const int col = bcol + wn * 64 + n * 16 + rl;
        const float wsc = ws[col];
        const float bv  = bias[col];
#pragma unroll
        for (int m = 0; m < 8; ++m) {
#pragma unroll
            for (int j = 0; j < 4; ++j) {
                const int row = brow + wm * 128 + m * 16 + rg * 4 + j;
                out[(size_t)row * 2048 + col] =
                    (float)acc[m][n][j] * xs[row] * wsc + bv;
            }
        }
    }
#undef ST_A
#undef ST_B
#undef FRAG_A
#undef FRAG_B
#undef MFMA16
#undef BAR
#undef LGKM
}

// ---------------------------------------------------------------------------
extern "C" void kernel_launch(void* const* d_in, const int* in_sizes, int n_in,
                              void* d_out, int out_size, void* d_ws, size_t ws_size,
                              hipStream_t stream) {
    const float* x    = (const float*)d_in[0];   // [B,N,D] = [4,4096,2048]
    const float* w    = (const float*)d_in[1];   // [O,D]   = [2048,2048]
    const float* bias = (const float*)d_in[2];   // [O]
    float* out = (float*)d_out;

    const int D = 2048;
    const int O = in_sizes[2];                   // 2048
    const int M = in_sizes[0] / D;               // 16384

    char* wsb = (char*)d_ws;
    signed char* xq  = (signed char*)wsb;
    signed char* wqp = (signed char*)(wsb + (size_t)M * D);
    float* xs  = (float*)(wsb + (size_t)M * D + (size_t)O * D);
    float* wsc = (float*)(wsb + (size_t)M * D + (size_t)O * D + (size_t)M * 4);

    quant_rows_2048<<<M / 4, 256, 0, stream>>>(x, xq, xs, 1e-12f);
    quant_rows_2048<<<O / 4, 256, 0, stream>>>(w, wqp, wsc, 1e-8f / 127.0f);

    dim3 grid(O / 256, M / 256);   // (8, 64) = 512 blocks
    gemm_i8_pipe<<<grid, 512, 0, stream>>>(xq, wqp, xs, wsc, bias, out, D);
}

// Round 7
// 126.392 us; speedup vs baseline: 1.2711x; 1.2711x over previous
//
#include <hip/hip_runtime.h>
#include <stdint.h>
#include <stddef.h>

typedef int v4i __attribute__((ext_vector_type(4)));

#define GLOAD_LDS16(g, l) __builtin_amdgcn_global_load_lds( \
    (const __attribute__((address_space(1))) void*)(g),     \
    (__attribute__((address_space(3))) void*)(l), 16, 0, 0)

// ---------------------------------------------------------------------------
// Quantize rows of length 2048: one wave per row, 4 rows per 256-thread block.
// scale = max(amax/127, floorv); q = clip(rint(v/scale), -128, 127)
// ---------------------------------------------------------------------------
__device__ __forceinline__ int pack4(float4 f, float s) {
    int a = (int)rintf(f.x / s); a = a < -128 ? -128 : (a > 127 ? 127 : a);
    int b = (int)rintf(f.y / s); b = b < -128 ? -128 : (b > 127 ? 127 : b);
    int c = (int)rintf(f.z / s); c = c < -128 ? -128 : (c > 127 ? 127 : c);
    int d = (int)rintf(f.w / s); d = d < -128 ? -128 : (d > 127 ? 127 : d);
    return (a & 255) | ((b & 255) << 8) | ((c & 255) << 16) | ((d & 255) << 24);
}

__global__ __launch_bounds__(256) void quant_rows_2048(
    const float* __restrict__ in, signed char* __restrict__ q,
    float* __restrict__ scales, float floorv)
{
    const int lane = threadIdx.x & 63;
    const int row  = blockIdx.x * 4 + (threadIdx.x >> 6);
    const float* rp = in + (size_t)row * 2048;

    float4 v[8];
#pragma unroll
    for (int j = 0; j < 2; ++j) {
        const float4* p = (const float4*)(rp + j * 1024 + lane * 16);
#pragma unroll
        for (int i = 0; i < 4; ++i) v[j * 4 + i] = p[i];
    }
    float am = 0.0f;
#pragma unroll
    for (int i = 0; i < 8; ++i) {
        am = fmaxf(am, fabsf(v[i].x));
        am = fmaxf(am, fabsf(v[i].y));
        am = fmaxf(am, fabsf(v[i].z));
        am = fmaxf(am, fabsf(v[i].w));
    }
#pragma unroll
    for (int off = 32; off; off >>= 1) am = fmaxf(am, __shfl_xor(am, off));
    const float s = fmaxf(am / 127.0f, floorv);

#pragma unroll
    for (int j = 0; j < 2; ++j) {
        int4 pk;
        pk.x = pack4(v[j * 4 + 0], s);
        pk.y = pack4(v[j * 4 + 1], s);
        pk.z = pack4(v[j * 4 + 2], s);
        pk.w = pack4(v[j * 4 + 3], s);
        *(int4*)(q + (size_t)row * 2048 + j * 1024 + lane * 16) = pk;
    }
    if (lane == 0) scales[row] = s;
}

// ---------------------------------------------------------------------------
// int8 GEMM — occupancy-first structure (m97-style simple loop, 2 blocks/CU):
// 128x256 tile, BK=64, 512 thr = 8 waves (2M x 4N), per-wave 64x64 via
// 4x4 frags of mfma_i32_16x16x64_i8 (acc = 64 VGPR). Double-buffered LDS:
// A 2x8KB + B 2x16KB = 48 KB -> 2 blocks/CU; __launch_bounds__(512,4)
// targets <=128 regs -> 4 waves/SIMD, 16 waves/CU. Per tile:
// {stage t+1 -> buf^1 (3 gload_lds); 8 ds_read frags of buf; 16 MFMA;
//  __syncthreads()}  — compiler emits fine lgkm waits; the vmcnt(0) drain
// at the barrier is covered by the other resident block (m114 TLP).
// Swizzle: slot s of row r holds global chunk s ^ ((r>>1)&3): 2-way = free.
// ---------------------------------------------------------------------------
__global__ __launch_bounds__(512, 4) void gemm_i8_occ(
    const signed char* __restrict__ xq, const signed char* __restrict__ wq,
    const float* __restrict__ xs, const float* __restrict__ ws,
    const float* __restrict__ bias, float* __restrict__ out, int K)
{
    __shared__ __align__(16) signed char lds[49152]; // A[2][8K] @0, B[2][16K] @16K

    const int tid  = threadIdx.x;
    const int lane = tid & 63;
    const int wid  = tid >> 6;
    const int wm   = wid >> 2;        // 0..1
    const int wn   = wid & 3;         // 0..3

    const int nwg  = gridDim.x * gridDim.y;
    int orig = blockIdx.y * gridDim.x + blockIdx.x;
    int swz  = ((nwg & 7) == 0) ? ((orig & 7) * (nwg >> 3) + (orig >> 3)) : orig;
    const int brow = (swz / gridDim.x) * 128;
    const int bcol = (swz % gridDim.x) * 256;

    // staging: thread -> (row = tid>>2 in 0..127, chunk = tid&3)
    const int gch  = (((tid & 3) ^ ((tid >> 3) & 3)) << 4);      // swizzled src byte
    const int lofs = tid << 4;                                   // linear LDS dest
    const signed char* gA  = xq + (size_t)(brow + (tid >> 2)) * K;
    const signed char* gB0 = wq + (size_t)(bcol + (tid >> 2)) * K;
    const signed char* gB1 = wq + (size_t)(bcol + 128 + (tid >> 2)) * K;

#define ST_A(tt, bb)  GLOAD_LDS16(gA  + (size_t)(tt) * 64 + gch, lds + ((bb) ? 8192 : 0) + lofs)
#define ST_B0(tt, bb) GLOAD_LDS16(gB0 + (size_t)(tt) * 64 + gch, lds + 16384 + ((bb) ? 16384 : 0) + lofs)
#define ST_B1(tt, bb) GLOAD_LDS16(gB1 + (size_t)(tt) * 64 + gch, lds + 24576 + ((bb) ? 16384 : 0) + lofs)

    const int rl   = lane & 15;
    const int ko   = lane >> 4;
    const int slot = ((ko ^ ((rl >> 1) & 3)) << 4);

#define FRAG_A(bb, r) (*(const v4i*)(lds + (((bb) ? 8192 : 0) + (r) * 64 + slot)))
#define FRAG_B(bb, r) (*(const v4i*)(lds + (16384 + ((bb) ? 16384 : 0) + (r) * 64 + slot)))

    v4i acc[4][4] = {};
    const int ar = wm * 64 + rl;
    const int br = wn * 64 + rl;

    // ---- prologue: stage tile 0 into buf 0
    ST_A(0, 0); ST_B0(0, 0); ST_B1(0, 0);
    __syncthreads();

    const int NT = K >> 6;   // 32
    for (int t = 0; t < NT; ++t) {
        const int buf = t & 1;
        if (t + 1 < NT) {
            ST_A(t + 1, buf ^ 1);
            ST_B0(t + 1, buf ^ 1);
            ST_B1(t + 1, buf ^ 1);
        }
        v4i af[4], bf[4];
#pragma unroll
        for (int m = 0; m < 4; ++m) af[m] = FRAG_A(buf, ar + m * 16);
#pragma unroll
        for (int n = 0; n < 4; ++n) bf[n] = FRAG_B(buf, br + n * 16);
#pragma unroll
        for (int m = 0; m < 4; ++m)
#pragma unroll
            for (int n = 0; n < 4; ++n)
                acc[m][n] = __builtin_amdgcn_mfma_i32_16x16x64_i8(
                    af[m], bf[n], acc[m][n], 0, 0, 0);
        __syncthreads();
    }

    // ---- epilogue: C/D layout col = lane&15, row = (lane>>4)*4 + j
    const int rg = lane >> 4;
#pragma unroll
    for (int n = 0; n < 4; ++n) {
        const int col = bcol + wn * 64 + n * 16 + rl;
        const float wsc = ws[col];
        const float bv  = bias[col];
#pragma unroll
        for (int m = 0; m < 4; ++m) {
#pragma unroll
            for (int j = 0; j < 4; ++j) {
                const int row = brow + wm * 64 + m * 16 + rg * 4 + j;
                out[(size_t)row * 2048 + col] =
                    (float)acc[m][n][j] * xs[row] * wsc + bv;
            }
        }
    }
#undef ST_A
#undef ST_B0
#undef ST_B1
#undef FRAG_A
#undef FRAG_B
}

// ---------------------------------------------------------------------------
extern "C" void kernel_launch(void* const* d_in, const int* in_sizes, int n_in,
                              void* d_out, int out_size, void* d_ws, size_t ws_size,
                              hipStream_t stream) {
    const float* x    = (const float*)d_in[0];   // [B,N,D] = [4,4096,2048]
    const float* w    = (const float*)d_in[1];   // [O,D]   = [2048,2048]
    const float* bias = (const float*)d_in[2];   // [O]
    float* out = (float*)d_out;

    const int D = 2048;
    const int O = in_sizes[2];                   // 2048
    const int M = in_sizes[0] / D;               // 16384

    char* wsb = (char*)d_ws;
    signed char* xq  = (signed char*)wsb;
    signed char* wqp = (signed char*)(wsb + (size_t)M * D);
    float* xs  = (float*)(wsb + (size_t)M * D + (size_t)O * D);
    float* wsc = (float*)(wsb + (size_t)M * D + (size_t)O * D + (size_t)M * 4);

    quant_rows_2048<<<M / 4, 256, 0, stream>>>(x, xq, xs, 1e-12f);
    quant_rows_2048<<<O / 4, 256, 0, stream>>>(w, wqp, wsc, 1e-8f / 127.0f);

    dim3 grid(O / 256, M / 128);   // (8, 128) = 1024 blocks, %8 == 0
    gemm_i8_occ<<<grid, 512, 0, stream>>>(xq, wqp, xs, wsc, bias, out, D);
}